// Round 11
// baseline (120.046 us; speedup 1.0000x reference)
//
#include <hip/hip_runtime.h>
#include <hip/hip_bf16.h>

#define NN 384
#define HH 768
#define HP 772   // padded LDS row (772%8==4 -> row bases spread over banks, 16B aligned)
#define NB 256   // persistent grid: 256 blocks
#define L2E 1.4426950408889634f
#define TWO_L2E 2.8853900817779268f
#define INV_SQRT_H 0.03608439182435161f

__device__ __forceinline__ float exp2_hw(float x) { return __builtin_amdgcn_exp2f(x); }
__device__ __forceinline__ float rcp_hw(float x) { return __builtin_amdgcn_rcpf(x); }

// Coherent-point accessors for ALL cross-phase data (relaxed agent-scope atomics,
// no cache maintenance). Round-10 lesson: normal cached stores to att/attT are
// NOT cross-XCD visible inside one kernel — every producer->consumer tensor that
// crosses a grid barrier must go through these.
__device__ __forceinline__ float ld_nc(const float* p) {
    return __hip_atomic_load(p, __ATOMIC_RELAXED, __HIP_MEMORY_SCOPE_AGENT);
}
__device__ __forceinline__ void st_nc(float* p, float v) {
    __hip_atomic_store(p, v, __ATOMIC_RELAXED, __HIP_MEMORY_SCOPE_AGENT);
}

// Grid barrier: relaxed arrival RMW + relaxed LOAD-ONLY spin (rounds 7-9 tuned:
// RMW-spin serializes at the coherent point; acquire-anything storms buffer_inv).
__device__ __forceinline__ void grid_bar(unsigned* bar, int idx, unsigned nb) {
    __syncthreads();
    if (threadIdx.x == 0) {
        unsigned* cnt = bar + idx * 64;
        unsigned* flg = cnt + 32;
        unsigned old = __hip_atomic_fetch_add(cnt, 1u, __ATOMIC_RELAXED, __HIP_MEMORY_SCOPE_AGENT);
        if (old == nb - 1u) {
            __hip_atomic_store(flg, 1u, __ATOMIC_RELAXED, __HIP_MEMORY_SCOPE_AGENT);
        } else {
            while (__hip_atomic_load(flg, __ATOMIC_RELAXED, __HIP_MEMORY_SCOPE_AGENT) == 0u) {
                __builtin_amdgcn_s_sleep(1);
            }
        }
    }
    __syncthreads();
}

// ---------------- single persistent kernel: att + stats + typ + w + proto + cls ----
__global__ __launch_bounds__(256) void k_fused(const float* __restrict__ X,
                                               const float* __restrict__ Y,
                                               const float* __restrict__ W,
                                               const float* __restrict__ bias,
                                               float* __restrict__ att,
                                               float* __restrict__ attT,
                                               float* rowM, float* rowRS, float* colM, float* colRS,
                                               float* hyper_typ, float* hypo_typ,
                                               float* w_hyper, float* w_hypo,
                                               float* hp, float* hq,
                                               unsigned* bar, float* out) {
    __shared__ float xs[8 * HP];
    __shared__ float ys[8 * HP];
    __shared__ float part[4][64];
    const int b = blockIdx.x, t = threadIdx.x;
    const unsigned nb = gridDim.x;
    const int wv = t >> 6, ln = t & 63;
    const int gw = (b << 2) + wv;          // global wave id
    const int nw = nb << 2;

    // ---- Phase 0: att[i][j] = sum_k tanh(x_i[k]*y_j[k]) / sqrt(H). 2304 8x8 tiles. ----
    for (int tile = b; tile < 48 * 48; tile += NB) {
        const int i0 = (tile / 48) * 8, j0 = (tile % 48) * 8;
        __syncthreads();   // previous tile's part[]/LDS reads complete before restage
        const float4* gx = (const float4*)(X + i0 * HH);
        const float4* gy = (const float4*)(Y + j0 * HH);
#pragma unroll
        for (int p = 0; p < 6; p++) {
            int e = t + p * 256;
            int r = e / 192, c = e - r * 192;
            float4 vx = gx[e];
            float4 vy = gy[e];
            ((float4*)(xs + r * HP))[c] = vx;
            vy.x *= TWO_L2E; vy.y *= TWO_L2E; vy.z *= TWO_L2E; vy.w *= TWO_L2E;
            ((float4*)(ys + r * HP))[c] = vy;
        }
        __syncthreads();

        const int i = ln >> 3, j = ln & 7;
        const float4* xr = (const float4*)(xs + i * HP) + wv * 48;
        const float4* yr = (const float4*)(ys + j * HP) + wv * 48;
        float a0 = 0.f, a1 = 0.f, a2 = 0.f, a3 = 0.f;
#pragma unroll 8
        for (int m = 0; m < 48; m++) {
            float4 a = xr[m];
            float4 bb = yr[m];
            a0 += rcp_hw(exp2_hw(a.x * bb.x) + 1.f);
            a1 += rcp_hw(exp2_hw(a.y * bb.y) + 1.f);
            a2 += rcp_hw(exp2_hw(a.z * bb.z) + 1.f);
            a3 += rcp_hw(exp2_hw(a.w * bb.w) + 1.f);
        }
        part[wv][ln] = (a0 + a1) + (a2 + a3);
        __syncthreads();
        if (t < 64) {
            float s = part[0][t] + part[1][t] + part[2][t] + part[3][t];
            int ii = t >> 3, jj = t & 7;
            float v = (768.f - 2.f * s) * INV_SQRT_H;
            st_nc(att + (i0 + ii) * NN + (j0 + jj), v);     // coherent-point write:
            st_nc(attT + (j0 + jj) * NN + (i0 + ii), v);    // cross-XCD visible after bar
        }
    }
    grid_bar(bar, 0, nb);

    // ---- Phase A: softmax stats. items 0..383 = rows (att), 384..767 = cols (attT) ----
    for (int it = gw; it < 2 * NN; it += nw) {
        const float* base = (it < NN) ? (att + it * NN) : (attT + (it - NN) * NN);
        float v0 = ld_nc(base + ln),       v1 = ld_nc(base + ln + 64),  v2 = ld_nc(base + ln + 128);
        float v3 = ld_nc(base + ln + 192), v4 = ld_nc(base + ln + 256), v5 = ld_nc(base + ln + 320);
        float m = fmaxf(fmaxf(fmaxf(v0, v1), fmaxf(v2, v3)), fmaxf(v4, v5));
#pragma unroll
        for (int o = 32; o; o >>= 1) m = fmaxf(m, __shfl_xor(m, o, 64));
        float s = exp2_hw((v0 - m) * L2E) + exp2_hw((v1 - m) * L2E) + exp2_hw((v2 - m) * L2E)
                + exp2_hw((v3 - m) * L2E) + exp2_hw((v4 - m) * L2E) + exp2_hw((v5 - m) * L2E);
#pragma unroll
        for (int o = 32; o; o >>= 1) s += __shfl_xor(s, o, 64);
        if (ln == 0) {
            float rs = 1.f / s;
            if (it < NN) { st_nc(rowM + it, m); st_nc(rowRS + it, rs); }
            else         { st_nc(colM + it - NN, m); st_nc(colRS + it - NN, rs); }
        }
    }
    grid_bar(bar, 1, nb);

    // ---- Phase B: typicalness ----
    for (int it = gw; it < 2 * NN; it += nw) {
        float s = 0.f;
        if (it < NN) {
            const float* base = attT + it * NN;
#pragma unroll
            for (int k = 0; k < 6; k++) {
                int i = ln + 64 * k;
                s += exp2_hw((ld_nc(base + i) - ld_nc(rowM + i)) * L2E) * ld_nc(rowRS + i);
            }
        } else {
            const float* base = att + (it - NN) * NN;
#pragma unroll
            for (int k = 0; k < 6; k++) {
                int j = ln + 64 * k;
                s += exp2_hw((ld_nc(base + j) - ld_nc(colM + j)) * L2E) * ld_nc(colRS + j);
            }
        }
#pragma unroll
        for (int o = 32; o; o >>= 1) s += __shfl_xor(s, o, 64);
        if (ln == 0) {
            if (it < NN) st_nc(hyper_typ + it, s * (1.f / NN));
            else         st_nc(hypo_typ + it - NN, s * (1.f / NN));
        }
    }
    grid_bar(bar, 2, nb);

    // ---- Phase C: attention weights ----
    for (int it = gw; it < 2 * NN; it += nw) {
        float s = 0.f;
        if (it < NN) {
            const float* base = attT + it * NN;
#pragma unroll
            for (int k = 0; k < 6; k++) {
                int i = ln + 64 * k;
                s += exp2_hw((ld_nc(base + i) - ld_nc(rowM + i)) * L2E) * ld_nc(rowRS + i) * ld_nc(hypo_typ + i);
            }
        } else {
            const float* base = att + (it - NN) * NN;
#pragma unroll
            for (int k = 0; k < 6; k++) {
                int j = ln + 64 * k;
                s += exp2_hw((ld_nc(base + j) - ld_nc(colM + j)) * L2E) * ld_nc(colRS + j) * ld_nc(hyper_typ + j);
            }
        }
#pragma unroll
        for (int o = 32; o; o >>= 1) s += __shfl_xor(s, o, 64);
        if (ln == 0) {
            if (it < NN) st_nc(w_hyper + it, s);
            else         st_nc(w_hypo + it - NN, s);
        }
    }
    grid_bar(bar, 3, nb);

    // ---- Phase D: prototypes (blocks 0..23) ----
    if (b < 24) {
        bool hyper = b < 12;
        int bb = hyper ? b : b - 12;
        int d = bb * 64 + ln;
        float s = 0.f;
        if (hyper) {
            for (int j = wv * 96; j < wv * 96 + 96; j++) s += ld_nc(w_hyper + j) * Y[j * HH + d];
        } else {
            for (int i = wv * 96; i < wv * 96 + 96; i++) s += ld_nc(w_hypo + i) * X[i * HH + d];
        }
        part[wv][ln] = s;
        __syncthreads();
        if (t < 64) {
            float S = part[0][t] + part[1][t] + part[2][t] + part[3][t];
            if (hyper) st_nc(hp + bb * 64 + t, S);
            else       st_nc(hq + bb * 64 + t, S);
        }
    }
    grid_bar(bar, 4, nb);

    // ---- Phase E: classifier (block 0) ----
    if (b == 0) {
        float acc0 = 0.f, acc1 = 0.f, acc2 = 0.f;
        for (int d = t; d < 4 * HH; d += 256) {
            int seg = d / HH, r = d - seg * HH;
            float hpv = ld_nc(hp + r), hqv = ld_nc(hq + r);
            float f = (seg == 0) ? hpv : (seg == 1) ? hqv : (seg == 2) ? (hpv - hqv) : (hpv * hqv);
            acc0 += W[d] * f;
            acc1 += W[3072 + d] * f;
            acc2 += W[6144 + d] * f;
        }
#pragma unroll
        for (int o = 32; o; o >>= 1) {
            acc0 += __shfl_xor(acc0, o, 64);
            acc1 += __shfl_xor(acc1, o, 64);
            acc2 += __shfl_xor(acc2, o, 64);
        }
        if (ln == 0) { part[0][wv] = acc0; part[1][wv] = acc1; part[2][wv] = acc2; }
        __syncthreads();
        if (t < 3) {
            float S = part[t][0] + part[t][1] + part[t][2] + part[t][3] + bias[t];
            out[t] = S;
        }
    }
}

extern "C" void kernel_launch(void* const* d_in, const int* in_sizes, int n_in,
                              void* d_out, int out_size, void* d_ws, size_t ws_size,
                              hipStream_t stream) {
    const float* X = (const float*)d_in[0];   // hypo_embeddings [384,768] fp32
    const float* Y = (const float*)d_in[1];   // hyper_embeddings [384,768] fp32
    const float* W = (const float*)d_in[2];   // W_cls [3,3072] fp32
    const float* B = (const float*)d_in[3];   // b_cls [3] fp32
    float* out = (float*)d_out;               // fp32 output

    float* ws = (float*)d_ws;
    float* att       = ws;                  // 147456
    float* attT      = att + NN * NN;       // 147456
    float* rowM      = attT + NN * NN;      // 384
    float* rowRS     = rowM + NN;
    float* colM      = rowRS + NN;
    float* colRS     = colM + NN;
    float* hyper_typ = colRS + NN;
    float* hypo_typ  = hyper_typ + NN;
    float* w_hyper   = hypo_typ + NN;
    float* w_hypo    = w_hyper + NN;
    float* hp        = w_hypo + NN;         // 768
    float* hq        = hp + HH;             // 768
    unsigned* bar    = (unsigned*)(hq + HH); // 5 barriers x 64 u32

    hipMemsetAsync(bar, 0, 5 * 64 * sizeof(unsigned), stream);
    k_fused<<<NB, 256, 0, stream>>>(X, Y, W, B, att, attT,
                                    rowM, rowRS, colM, colRS,
                                    hyper_typ, hypo_typ, w_hyper, w_hypo,
                                    hp, hq, bar, out);
}